// Round 13
// baseline (1365.720 us; speedup 1.0000x reference)
//
#include <hip/hip_runtime.h>
#include <hip/hip_bf16.h>

using bf16 = __hip_bfloat16;
typedef unsigned short u16;
typedef unsigned int u32;
typedef __attribute__((ext_vector_type(8))) short short8;
typedef __attribute__((ext_vector_type(4))) float floatx4;

#define DEVI __device__ __forceinline__

constexpr int B = 64, T = 24, N = 256, F1 = 64, F2 = 128;

DEVI float b2f(bf16 v) { return __bfloat162float(v); }
DEVI float b2fu(u16 u) { return __uint_as_float(((u32)u) << 16); }
DEVI u16 f2b(float f) {                  // RNE float->bf16 bits
    u32 u = __float_as_uint(f);
    u32 r = (u + 0x7FFF + ((u >> 16) & 1)) >> 16;
    return (u16)r;
}
DEVI float hsig(float x) { x = x * 0.2f + 0.5f; return fminf(fmaxf(x, 0.f), 1.f); }

#if __has_builtin(__builtin_amdgcn_global_load_lds)
#define ASYNC16(gsrc, ldst)                                                            \
    __builtin_amdgcn_global_load_lds((const __attribute__((address_space(1))) u32*)(gsrc), \
                                     (__attribute__((address_space(3))) u32*)(ldst), 16, 0, 0)
#define HAVE_ASYNC 1
#else
#define HAVE_ASYNC 0
#endif

DEVI float read_in(const void* p, long i, int isbf) {
    return isbf ? b2f(((const bf16*)p)[i]) : ((const float*)p)[i];
}

// ---------- dtype detection ----------
__global__ void init_flag(int* flag) { *flag = 1; }
__global__ void detect_scan(const u16* __restrict__ xu, int* __restrict__ flag) {
    int i0 = blockIdx.x * 2048 + threadIdx.x;
    int hit = 0;
    for (int i = i0; i < (blockIdx.x + 1) * 2048; i += 256)
        if (((xu[i] >> 7) & 0xFF) == 0xFF) hit = 1;
    if (hit) *flag = 0;
}

// ---------- fused setup ----------
struct CvtDesc { const void* src; float* dst; int n; };
struct CvtPack { CvtDesc d[8]; };
__global__ void cvt_pack(CvtPack p, const int* __restrict__ flag) {
    CvtDesc c = p.d[blockIdx.x];
    int isbf = *flag;
    for (int i = threadIdx.x; i < c.n; i += 256)
        c.dst[i] = c.src ? read_in(c.src, i, isbf) : 0.f;
}

// ---------- LSTM weight repack: Wt[g][k], k = kn*(CIN+F)+c ; c<CIN -> kx else kh ----------
__global__ void repack_w(const void* __restrict__ kxr, const void* __restrict__ khr,
                         u16* __restrict__ Wt, int CIN, int F, const int* __restrict__ flag) {
    int NG = 4 * F, CH = CIN + F, K = 3 * CH;
    int idx = blockIdx.x * 256 + threadIdx.x;
    if (idx >= NG * K) return;
    int g = idx / K, k = idx - g * K;
    int kn = k / CH, c = k - kn * CH;
    int isbf = *flag;
    float v = (c < CIN) ? read_in(kxr, (long)(kn * CIN + c) * NG + g, isbf)
                        : read_in(khr, (long)(kn * F + (c - CIN)) * NG + g, isbf);
    Wt[(long)g * K + k] = f2b(v);
}

// ---------- conv2 weight repack ----------
__global__ void repack_w2(const void* __restrict__ w2r, u16* __restrict__ w2b,
                          const int* __restrict__ flag) {
    int idx = blockIdx.x * 256 + threadIdx.x;
    if (idx >= 64 * 576) return;
    int f = idx / 576, k = idx - f * 576;
    int kt = k / 192, rem = k - kt * 192, kn = rem >> 6, c = rem & 63;
    float v = read_in(w2r, (long)((kt * 3 + kn) * 64 + c) * 64 + f, *flag);
    w2b[(long)f * 576 + k] = f2b(v);
}

// ---------- conv1, all 26 slices in one launch: slice s <-> tt = s-1 ----------
__global__ __launch_bounds__(256)
void conv1_all(const void* __restrict__ xraw, const float* __restrict__ w1c,
               const float* __restrict__ b1v, u16* __restrict__ c1all,
               const int* __restrict__ flag) {
    __shared__ float sxw[3 * 260];
    int s = blockIdx.x, b = blockIdx.y, tid = threadIdx.x;
    int tt = s - 1;
    u16* dst = c1all + ((long)s * B + b) * N * 64;
    if (tt < 0 || tt >= T) {
        for (int i = tid; i < N * 64 / 4; i += 256) *(uint2*)&dst[i * 4] = uint2{0, 0};
        return;
    }
    int isbf = *flag;
    for (int i = tid; i < 3 * 258; i += 256) {
        int r = i / 258, cc = i - r * 258;
        int ttt = tt - 1 + r, nn = cc - 1;
        float v = 0.f;
        if (ttt >= 0 && ttt < T && nn >= 0 && nn < N)
            v = read_in(xraw, (long)(b * T + ttt) * N + nn, isbf);
        sxw[r * 260 + cc] = v;
    }
    __syncthreads();
    int c = tid & 63, ngq = tid >> 6;
    float w[9];
#pragma unroll
    for (int j = 0; j < 9; j++) w[j] = w1c[j * 64 + c];
    float bias = b1v[c];
    for (int j = 0; j < 64; j++) {
        int n = ngq * 64 + j;
        float v = bias;
#pragma unroll
        for (int dt = 0; dt < 3; dt++)
#pragma unroll
            for (int dn = 0; dn < 3; dn++)
                v += sxw[dt * 260 + n + dn] * w[dt * 3 + dn];
        dst[n * 64 + c] = f2b(v);
    }
}

// ---------- MFMA conv2, all 24 t: LDS-staged B, conflict-free [u][g] layout ----------
__global__ __launch_bounds__(256)
void conv_mfma(const u16* __restrict__ c1all, const u16* __restrict__ w2b,
               const float* __restrict__ b2v, u16* __restrict__ xs24,
               float* __restrict__ ssq) {
    constexpr int CP1 = 72;
    __shared__ __align__(16) u16 win1[3 * 66 * CP1];
    __shared__ __align__(16) u16 bch[2 * 2048];
    __shared__ float red[256];

    int tid = threadIdx.x;
    int bb = blockIdx.y, n0 = blockIdx.x * 64, t = blockIdx.z;
    int w = tid >> 6, l15 = tid & 15, q = (tid >> 4) & 3;

    for (int i = tid; i < 3 * 66 * 8; i += 256) {
        int u = i & 7, rr = i >> 3;
        int kt = rr / 66, r1 = rr - kt * 66;
        int nn = n0 - 1 + r1;
        uint4 v{0, 0, 0, 0};
        if (nn >= 0 && nn < N)
            v = *(const uint4*)&c1all[((((long)(t + kt)) * B + bb) * N + nn) * 64 + u * 8];
        *(uint4*)&win1[(kt * 66 + r1) * CP1 + u * 8] = v;
    }

    // stage chunk kk: unit (g=col, u=k-slice) at bch[(u*64+g)*8]; per wave u uniform, g=lane
    auto stage = [&](int kk, int bufi) {
        int u = tid >> 6, g = tid & 63;
#if HAVE_ASYNC
        ASYNC16(w2b + (long)g * 576 + kk * 32 + u * 8, &bch[bufi * 2048 + (u * 64 + g) * 8]);
#else
        uint4 v = *(const uint4*)(w2b + (long)g * 576 + kk * 32 + u * 8);
        *(uint4*)&bch[bufi * 2048 + (u * 64 + g) * 8] = v;
#endif
    };
    stage(0, 0);
    __syncthreads();

    floatx4 acc[4] = {};
    for (int kk = 0; kk < 18; ++kk) {
        int cur = kk & 1;
        if (kk + 1 < 18) stage(kk + 1, 1 - cur);
        int kbase = kk * 32;
        int kt = kbase / 192, rem = kbase - kt * 192, kn = rem >> 6, c0 = rem & 63;
        int gcol = w * 16 + l15;
        short8 bf = *(const short8*)&bch[cur * 2048 + (q * 64 + gcol) * 8];
#pragma unroll
        for (int mi = 0; mi < 4; mi++) {
            short8 af = *(const short8*)&win1[(kt * 66 + mi * 16 + l15 + kn) * CP1 + c0 + q * 8];
            acc[mi] = __builtin_amdgcn_mfma_f32_16x16x32_bf16(af, bf, acc[mi], 0, 0, 0);
        }
        __syncthreads();
    }

    u16* xslice = xs24 + (long)t * B * N * 64;
    int f = w * 16 + l15;
    float bias2 = b2v[f];
    float lsum = 0.f;
#pragma unroll
    for (int mi = 0; mi < 4; mi++)
#pragma unroll
        for (int r = 0; r < 4; r++) {
            int n = n0 + mi * 16 + q * 4 + r;
            float v = acc[mi][r] + bias2;
            lsum += v * v;
            xslice[((long)bb * N + n) * 64 + f] = f2b(v);
        }
    red[tid] = lsum; __syncthreads();
    for (int k = 128; k > 0; k >>= 1) {
        if (tid < k) red[tid] += red[tid + k];
        __syncthreads();
    }
    if (tid == 0) atomicAdd(&ssq[bb * T + t], red[0]);
}

// ---------- MFMA ConvLSTM step (R11 structure; bch in conflict-free [u][g] layout) ----------
// grid (4, B, 2): block z computes all 4 gates for features [z*FL, (z+1)*FL).
template<int CIN, int F, int FL>
__global__ __launch_bounds__(512, 4)
void lstm_mfma(const u16* __restrict__ xin, const u16* __restrict__ hprev,
               u16* __restrict__ hnext, float* __restrict__ cst,
               const u16* __restrict__ Wt, const float* __restrict__ bias,
               const float* __restrict__ ssqp, int t) {
    constexpr int CH = CIN + F;
    constexpr int CHP = CH + 8;
    constexpr int K = 3 * CH;
    constexpr int NK = K / 32;
    constexpr int NGL = 4 * FL;
    constexpr int NGP = NGL + 4;
    constexpr int NI = NGL / 128;
    constexpr int BCH = NGL * 32;
    constexpr int GLD_USH = 32 * NGP * 2;
    constexpr int UNION_USH = (2 * BCH > GLD_USH) ? 2 * BCH : GLD_USH;
    constexpr int LOGFL = (FL == 64) ? 6 : 5;
    constexpr int LOG_NGL = (NGL == 256) ? 8 : 7;

    __shared__ __align__(16) u16 win[66 * CHP];
    __shared__ __align__(16) u16 ubuf[UNION_USH];
    u16* bch = ubuf;
    float* Gld = (float*)ubuf;

    int tid = threadIdx.x;
    int bb = blockIdx.y, n0 = blockIdx.x * 64, z = blockIdx.z;
    int w = tid >> 6, l15 = tid & 15, q = (tid >> 4) & 3;

    float scale = 1.f;
    if (ssqp) scale = rsqrtf(fmaxf(ssqp[bb * T + t], 1e-12f));

    constexpr int GRP = CH / 4;
    for (int i = tid; i < 66 * GRP; i += 512) {
        int row = i / GRP, g4 = (i - row * GRP) * 4;
        int n = n0 + row - 1;
        uint2 v{};
        if (n >= 0 && n < N) {
            if (g4 < CIN) {
                v = *(const uint2*)&xin[((long)bb * N + n) * CIN + g4];
                if (ssqp) {
                    u16 e0 = f2b(b2fu((u16)(v.x & 0xFFFF)) * scale);
                    u16 e1 = f2b(b2fu((u16)(v.x >> 16)) * scale);
                    u16 e2 = f2b(b2fu((u16)(v.y & 0xFFFF)) * scale);
                    u16 e3 = f2b(b2fu((u16)(v.y >> 16)) * scale);
                    v.x = (u32)e0 | ((u32)e1 << 16);
                    v.y = (u32)e2 | ((u32)e3 << 16);
                }
            } else if (t > 0) {
                v = *(const uint2*)&hprev[((long)bb * N + n) * F + (g4 - CIN)];
            }
        }
        *(uint2*)&win[row * CHP + g4] = v;
    }

    // stage chunk kk: unit (g=local col, u=k-slice) at bch[(u*NGL+g)*8]
    auto stage = [&](int kk, int bufi) {
#pragma unroll
        for (int it = 0; it < (4 * NGL) / 512; ++it) {
            int U = it * 512 + tid;
            int u = U >> LOG_NGL, g = U & (NGL - 1);
            int gt = g >> LOGFL, fl = g & (FL - 1);
            long gr = (long)gt * F + z * FL + fl;
#if HAVE_ASYNC
            ASYNC16(Wt + gr * K + kk * 32 + u * 8, &bch[bufi * BCH + (u * NGL + g) * 8]);
#else
            uint4 v = *(const uint4*)(Wt + gr * K + kk * 32 + u * 8);
            *(uint4*)&bch[bufi * BCH + (u * NGL + g) * 8] = v;
#endif
        }
    };
    stage(0, 0);
    __syncthreads();

    floatx4 acc[4][NI] = {};
    for (int kk = 0; kk < NK; ++kk) {
        int cur = kk & 1;
        if (kk + 1 < NK) stage(kk + 1, 1 - cur);
        int kbase = kk * 32;
        int kn = kbase / CH, c0 = kbase - kn * CH;
        short8 af[4];
#pragma unroll
        for (int mi = 0; mi < 4; mi++)
            af[mi] = *(const short8*)&win[(mi * 16 + l15 + kn) * CHP + c0 + q * 8];
#pragma unroll
        for (int ni = 0; ni < NI; ni++) {
            int r = w * (NI * 16) + ni * 16 + l15;
            short8 bf = *(const short8*)&bch[cur * BCH + (q * NGL + r) * 8];
#pragma unroll
            for (int mi = 0; mi < 4; mi++)
                acc[mi][ni] = __builtin_amdgcn_mfma_f32_16x16x32_bf16(af[mi], bf, acc[mi][ni], 0, 0, 0);
        }
        __syncthreads();
    }

    for (int h = 0; h < 2; ++h) {
#pragma unroll
        for (int mi2 = 0; mi2 < 2; ++mi2) {
            int mi = h * 2 + mi2;
#pragma unroll
            for (int ni = 0; ni < NI; ni++)
#pragma unroll
                for (int r = 0; r < 4; r++)
                    Gld[(mi2 * 16 + q * 4 + r) * NGP + w * (NI * 16) + ni * 16 + l15] = acc[mi][ni][r];
        }
        __syncthreads();
        for (int i = tid; i < 32 * FL; i += 512) {
            int m = i >> LOGFL, fl = i & (FL - 1);
            int fz = z * FL + fl;
            float gi = Gld[m * NGP + fl]          + bias[fz];
            float gf = Gld[m * NGP + FL + fl]     + bias[F + fz];
            float gc = Gld[m * NGP + 2 * FL + fl] + bias[2 * F + fz];
            float go = Gld[m * NGP + 3 * FL + fl] + bias[3 * F + fz];
            int n = n0 + h * 32 + m;
            long ci = ((long)bb * N + n) * F + fz;
            float cp = (t > 0) ? cst[ci] : 0.f;
            float iv = hsig(gi), fv = hsig(gf), ov = hsig(go);
            float cn = fv * cp + iv * tanhf(gc);
            cst[ci] = cn;
            hnext[ci] = f2b(ov * tanhf(cn));
        }
        __syncthreads();
    }
}

// ---------- final: l2norm per b over N*F2 (bf16 in), project 128->1, flag-dtype store ----------
__global__ void final_kernel(const u16* __restrict__ hT, const float* __restrict__ fcw,
                             const float* __restrict__ fcb, void* __restrict__ out,
                             const int* __restrict__ flag) {
    __shared__ float red[256];
    int b = blockIdx.x, tid = threadIdx.x;
    const u16* hb = hT + (long)b * N * 128;
    float s = 0.f;
    for (int i = tid; i < N * 128; i += 256) { float v = b2fu(hb[i]); s += v * v; }
    red[tid] = s; __syncthreads();
    for (int k = 128; k > 0; k >>= 1) {
        if (tid < k) red[tid] += red[tid + k];
        __syncthreads();
    }
    float scale = rsqrtf(fmaxf(red[0], 1e-12f));
    int n = tid;
    float acc = fcb[0];
    for (int c = 0; c < 128; c++) acc += b2fu(hb[n * 128 + c]) * scale * fcw[c];
    if (*flag) ((bf16*)out)[b * N + n] = __float2bfloat16(acc);
    else       ((float*)out)[b * N + n] = acc;
}

extern "C" void kernel_launch(void* const* d_in, const int* in_sizes, int n_in,
                              void* d_out, int out_size, void* d_ws, size_t ws_size,
                              hipStream_t stream) {
    float* ws = (float*)d_ws;
    u16* xs24   = (u16*)ws;                 // 24*B*N*64 u16 = 12,582,912 fl
    u16* c1all  = (u16*)(ws + 12582912);    // 26*B*N*64 u16 = 13,631,488 fl -> 26,214,400
    u16* h1A    = (u16*)(ws + 26214400);    // B*N*64 u16 = 524,288 fl
    u16* h1B    = (u16*)(ws + 26738688);    // 524,288 fl
    u16* h2A    = (u16*)(ws + 27262976);    // B*N*128 u16 = 1,048,576 fl
    u16* h2B    = (u16*)(ws + 28311552);    // 1,048,576 fl
    float* c1   = ws + 29360128;            // B*N*64 fl = 1,048,576
    float* c2   = ws + 30408704;            // B*N*128 fl = 2,097,152
    u16* Wt1    = (u16*)(ws + 32505856);    // 49,152 fl
    u16* Wt2    = (u16*)(ws + 32555008);    // 147,456 fl
    u16* w2b    = (u16*)(ws + 32702464);    // 18,432 fl
    float* w1c  = ws + 32720896;            // 576
    float* bb1  = ws + 32721472;            // 64
    float* bb2  = ws + 32721536;            // 64
    float* bg1  = ws + 32721600;            // 256
    float* bg2  = ws + 32721856;            // 512
    float* fcwf = ws + 32722368;            // 128
    float* fcbf = ws + 32722496;            // 1
    float* ssq  = ws + 32722497;            // 1536
    int*   flag = (int*)(ws + 32724033);    // total ~32.72M fl = 130.9 MB

    init_flag<<<1, 1, 0, stream>>>(flag);
    detect_scan<<<32, 256, 0, stream>>>((const u16*)d_in[0], flag);

    CvtPack pk;
    pk.d[0] = {d_in[1],  w1c,  576};
    pk.d[1] = {d_in[2],  bb1,  64};
    pk.d[2] = {d_in[4],  bb2,  64};
    pk.d[3] = {d_in[7],  bg1,  256};
    pk.d[4] = {d_in[10], bg2,  512};
    pk.d[5] = {d_in[11], fcwf, 128};
    pk.d[6] = {d_in[12], fcbf, 1};
    pk.d[7] = {nullptr,  ssq,  B * T};
    cvt_pack<<<8, 256, 0, stream>>>(pk, flag);

    repack_w<<<(256 * 384 + 255) / 256, 256, 0, stream>>>(d_in[5], d_in[6], Wt1, 64, 64, flag);
    repack_w<<<(512 * 576 + 255) / 256, 256, 0, stream>>>(d_in[8], d_in[9], Wt2, 64, 128, flag);
    repack_w2<<<(64 * 576 + 255) / 256, 256, 0, stream>>>(d_in[3], w2b, flag);

    conv1_all<<<dim3(26, B), 256, 0, stream>>>(d_in[0], w1c, bb1, c1all, flag);
    conv_mfma<<<dim3(4, B, 24), 256, 0, stream>>>(c1all, w2b, bb2, xs24, ssq);

    for (int t = 0; t < T; t++) {
        const u16* h1p = (t & 1) ? h1A : h1B;
        u16* h1n = (t & 1) ? h1B : h1A;
        lstm_mfma<64, 64, 32><<<dim3(4, B, 2), 512, 0, stream>>>(
            xs24 + (long)t * B * N * 64, h1p, h1n, c1, Wt1, bg1, ssq, t);
        const u16* h2p = (t & 1) ? h2A : h2B;
        u16* h2n = (t & 1) ? h2B : h2A;
        lstm_mfma<64, 128, 64><<<dim3(4, B, 2), 512, 0, stream>>>(
            h1n, h2p, h2n, c2, Wt2, bg2, nullptr, t);
    }
    // t=23 (odd) wrote h2B
    final_kernel<<<B, 256, 0, stream>>>(h2B, fcwf, fcbf, d_out, flag);
}

// Round 14
// 879.236 us; speedup vs baseline: 1.5533x; 1.5533x over previous
//
#include <hip/hip_runtime.h>
#include <hip/hip_bf16.h>

using bf16 = __hip_bfloat16;
typedef unsigned short u16;
typedef unsigned int u32;
typedef __attribute__((ext_vector_type(8))) short short8;
typedef __attribute__((ext_vector_type(4))) float floatx4;

#define DEVI __device__ __forceinline__

constexpr int B = 64, T = 24, N = 256, F1 = 64, F2 = 128;

DEVI float b2f(bf16 v) { return __bfloat162float(v); }
DEVI float b2fu(u16 u) { return __uint_as_float(((u32)u) << 16); }
DEVI u16 f2b(float f) {                  // RNE float->bf16 bits
    u32 u = __float_as_uint(f);
    u32 r = (u + 0x7FFF + ((u >> 16) & 1)) >> 16;
    return (u16)r;
}
DEVI float hsig(float x) { x = x * 0.2f + 0.5f; return fminf(fmaxf(x, 0.f), 1.f); }

#if __has_builtin(__builtin_amdgcn_global_load_lds)
#define ASYNC16(gsrc, ldst)                                                            \
    __builtin_amdgcn_global_load_lds((const __attribute__((address_space(1))) u32*)(gsrc), \
                                     (__attribute__((address_space(3))) u32*)(ldst), 16, 0, 0)
#define HAVE_ASYNC 1
#else
#define HAVE_ASYNC 0
#endif

DEVI float read_in(const void* p, long i, int isbf) {
    return isbf ? b2f(((const bf16*)p)[i]) : ((const float*)p)[i];
}

// ---------- dtype detection ----------
__global__ void init_flag(int* flag) { *flag = 1; }
__global__ void detect_scan(const u16* __restrict__ xu, int* __restrict__ flag) {
    int i0 = blockIdx.x * 2048 + threadIdx.x;
    int hit = 0;
    for (int i = i0; i < (blockIdx.x + 1) * 2048; i += 256)
        if (((xu[i] >> 7) & 0xFF) == 0xFF) hit = 1;
    if (hit) *flag = 0;
}

// ---------- fused setup ----------
struct CvtDesc { const void* src; float* dst; int n; };
struct CvtPack { CvtDesc d[8]; };
__global__ void cvt_pack(CvtPack p, const int* __restrict__ flag) {
    CvtDesc c = p.d[blockIdx.x];
    int isbf = *flag;
    for (int i = threadIdx.x; i < c.n; i += 256)
        c.dst[i] = c.src ? read_in(c.src, i, isbf) : 0.f;
}

// ---------- LSTM weight repack: Wt[g][k], k = kn*(CIN+F)+c ; c<CIN -> kx else kh ----------
__global__ void repack_w(const void* __restrict__ kxr, const void* __restrict__ khr,
                         u16* __restrict__ Wt, int CIN, int F, const int* __restrict__ flag) {
    int NG = 4 * F, CH = CIN + F, K = 3 * CH;
    int idx = blockIdx.x * 256 + threadIdx.x;
    if (idx >= NG * K) return;
    int g = idx / K, k = idx - g * K;
    int kn = k / CH, c = k - kn * CH;
    int isbf = *flag;
    float v = (c < CIN) ? read_in(kxr, (long)(kn * CIN + c) * NG + g, isbf)
                        : read_in(khr, (long)(kn * F + (c - CIN)) * NG + g, isbf);
    Wt[(long)g * K + k] = f2b(v);
}

// ---------- conv2 weight repack ----------
__global__ void repack_w2(const void* __restrict__ w2r, u16* __restrict__ w2b,
                          const int* __restrict__ flag) {
    int idx = blockIdx.x * 256 + threadIdx.x;
    if (idx >= 64 * 576) return;
    int f = idx / 576, k = idx - f * 576;
    int kt = k / 192, rem = k - kt * 192, kn = rem >> 6, c = rem & 63;
    float v = read_in(w2r, (long)((kt * 3 + kn) * 64 + c) * 64 + f, *flag);
    w2b[(long)f * 576 + k] = f2b(v);
}

// ---------- conv1, all 26 slices in one launch: slice s <-> tt = s-1 ----------
__global__ __launch_bounds__(256)
void conv1_all(const void* __restrict__ xraw, const float* __restrict__ w1c,
               const float* __restrict__ b1v, u16* __restrict__ c1all,
               const int* __restrict__ flag) {
    __shared__ float sxw[3 * 260];
    int s = blockIdx.x, b = blockIdx.y, tid = threadIdx.x;
    int tt = s - 1;
    u16* dst = c1all + ((long)s * B + b) * N * 64;
    if (tt < 0 || tt >= T) {
        for (int i = tid; i < N * 64 / 4; i += 256) *(uint2*)&dst[i * 4] = uint2{0, 0};
        return;
    }
    int isbf = *flag;
    for (int i = tid; i < 3 * 258; i += 256) {
        int r = i / 258, cc = i - r * 258;
        int ttt = tt - 1 + r, nn = cc - 1;
        float v = 0.f;
        if (ttt >= 0 && ttt < T && nn >= 0 && nn < N)
            v = read_in(xraw, (long)(b * T + ttt) * N + nn, isbf);
        sxw[r * 260 + cc] = v;
    }
    __syncthreads();
    int c = tid & 63, ngq = tid >> 6;
    float w[9];
#pragma unroll
    for (int j = 0; j < 9; j++) w[j] = w1c[j * 64 + c];
    float bias = b1v[c];
    for (int j = 0; j < 64; j++) {
        int n = ngq * 64 + j;
        float v = bias;
#pragma unroll
        for (int dt = 0; dt < 3; dt++)
#pragma unroll
            for (int dn = 0; dn < 3; dn++)
                v += sxw[dt * 260 + n + dn] * w[dt * 3 + dn];
        dst[n * 64 + c] = f2b(v);
    }
}

// ---------- MFMA conv2, all 24 t (verbatim R11: XOR-swizzle staged B) ----------
__global__ __launch_bounds__(256)
void conv_mfma(const u16* __restrict__ c1all, const u16* __restrict__ w2b,
               const float* __restrict__ b2v, u16* __restrict__ xs24,
               float* __restrict__ ssq) {
    constexpr int CP1 = 72;
    __shared__ __align__(16) u16 win1[3 * 66 * CP1];
    __shared__ __align__(16) u16 bch[2 * 2048];
    __shared__ float red[256];

    int tid = threadIdx.x;
    int bb = blockIdx.y, n0 = blockIdx.x * 64, t = blockIdx.z;
    int w = tid >> 6, l15 = tid & 15, q = (tid >> 4) & 3;

    for (int i = tid; i < 3 * 66 * 8; i += 256) {
        int u = i & 7, rr = i >> 3;
        int kt = rr / 66, r1 = rr - kt * 66;
        int nn = n0 - 1 + r1;
        uint4 v{0, 0, 0, 0};
        if (nn >= 0 && nn < N)
            v = *(const uint4*)&c1all[((((long)(t + kt)) * B + bb) * N + nn) * 64 + u * 8];
        *(uint4*)&win1[(kt * 66 + r1) * CP1 + u * 8] = v;
    }

    auto stage = [&](int kk, int bufi) {
        int g = tid >> 2, u = tid & 3;
        int k = kk * 32 + ((u ^ (g & 3)) << 3);
#if HAVE_ASYNC
        ASYNC16(w2b + (long)g * 576 + k, &bch[bufi * 2048 + tid * 8]);
#else
        uint4 v = *(const uint4*)(w2b + (long)g * 576 + k);
        *(uint4*)&bch[bufi * 2048 + tid * 8] = v;
#endif
    };
    stage(0, 0);
    __syncthreads();

    floatx4 acc[4] = {};
    for (int kk = 0; kk < 18; ++kk) {
        int cur = kk & 1;
        if (kk + 1 < 18) stage(kk + 1, 1 - cur);
        int kbase = kk * 32;
        int kt = kbase / 192, rem = kbase - kt * 192, kn = rem >> 6, c0 = rem & 63;
        int gcol = w * 16 + l15;
        short8 bf = *(const short8*)&bch[cur * 2048 + gcol * 32 + ((q ^ (gcol & 3)) << 3)];
#pragma unroll
        for (int mi = 0; mi < 4; mi++) {
            short8 af = *(const short8*)&win1[(kt * 66 + mi * 16 + l15 + kn) * CP1 + c0 + q * 8];
            acc[mi] = __builtin_amdgcn_mfma_f32_16x16x32_bf16(af, bf, acc[mi], 0, 0, 0);
        }
        __syncthreads();
    }

    u16* xslice = xs24 + (long)t * B * N * 64;
    int f = w * 16 + l15;
    float bias2 = b2v[f];
    float lsum = 0.f;
#pragma unroll
    for (int mi = 0; mi < 4; mi++)
#pragma unroll
        for (int r = 0; r < 4; r++) {
            int n = n0 + mi * 16 + q * 4 + r;
            float v = acc[mi][r] + bias2;
            lsum += v * v;
            xslice[((long)bb * N + n) * 64 + f] = f2b(v);
        }
    red[tid] = lsum; __syncthreads();
    for (int k = 128; k > 0; k >>= 1) {
        if (tid < k) red[tid] += red[tid + k];
        __syncthreads();
    }
    if (tid == 0) atomicAdd(&ssq[bb * T + t], red[0]);
}

// ---------- persistent lstm1 chain: 1 block owns (b, 64 cols) for all 24 steps ----------
// Span 112 cols [lo, lo+112), lo = max(0, n0-23): 23-col sacrificial halo each side.
// h in LDS (win h-cols), c in VGPRs, B weights fully in registers -> 2 barriers/t.
__global__ __launch_bounds__(512, 2)
void lstm1_chain(const u16* __restrict__ xs24, u16* __restrict__ h1all,
                 const u16* __restrict__ Wt, const float* __restrict__ bias,
                 const float* __restrict__ ssq) {
    constexpr int CHP = 136;                       // 128 ch + 8 pad
    constexpr int NGP = 260;                       // 256 gate cols + 4 pad
    __shared__ __align__(16) u16 win[114 * CHP];   // rows r <-> n = lo-1+r ; ch: x[0,64) h[64,128)
    __shared__ __align__(16) float Gld[112 * NGP]; // gate exchange (full span)

    int tid = threadIdx.x;
    int bb = blockIdx.y, n0 = blockIdx.x * 64;
    int lo = n0 - 23; if (lo < 0) lo = 0;
    int w = tid >> 6, l15 = tid & 15, q = (tid >> 4) & 3;

    // B into registers: wave w owns gate-cols [32w, 32w+32) as frags ni=0,1
    uint4 breg[2][12];
#pragma unroll
    for (int ni = 0; ni < 2; ni++) {
        int g = (2 * w + ni) * 16 + l15;
#pragma unroll
        for (int kk = 0; kk < 12; kk++)
            breg[ni][kk] = *(const uint4*)&Wt[(long)g * 384 + kk * 32 + q * 8];
    }

    float bi[2], bf_[2], bc[2], bo[2];   // epilogue biases for this thread's 2 f-slots? no: f varies per pair
    (void)bi; (void)bf_; (void)bc; (void)bo;

    // zero entire window (h-cols must start 0; x-cols overwritten below)
    for (int i = tid; i < 114 * CHP / 4; i += 512) *(uint2*)&win[i * 4] = uint2{0, 0};
    __syncthreads();

    // stage x(t) into win x-cols, scaled by l2norm factor
    auto stage_x = [&](int t) {
        float scale = rsqrtf(fmaxf(ssq[bb * T + t], 1e-12f));
        const u16* xsl = xs24 + (long)t * B * N * 64;
        for (int i = tid; i < 114 * 16; i += 512) {
            int r = i >> 4, gi = i & 15;
            int n = lo - 1 + r;
            uint2 v{};
            if (n >= 0 && n < N) {
                v = *(const uint2*)&xsl[((long)bb * N + n) * 64 + gi * 4];
                u16 e0 = f2b(b2fu((u16)(v.x & 0xFFFF)) * scale);
                u16 e1 = f2b(b2fu((u16)(v.x >> 16)) * scale);
                u16 e2 = f2b(b2fu((u16)(v.y & 0xFFFF)) * scale);
                u16 e3 = f2b(b2fu((u16)(v.y >> 16)) * scale);
                v.x = (u32)e0 | ((u32)e1 << 16);
                v.y = (u32)e2 | ((u32)e3 << 16);
            }
            *(uint2*)&win[r * CHP + gi * 4] = v;
        }
    };
    stage_x(0);
    __syncthreads();

    float cst[14];
#pragma unroll
    for (int j = 0; j < 14; j++) cst[j] = 0.f;

    for (int t = 0; t < T; ++t) {
        // GEMM: 7 m-tiles x 2 col-frags, K = 384 (12 chunks), B from regs, no barriers
        floatx4 acc[7][2] = {};
        for (int kk = 0; kk < 12; ++kk) {
            int kn = kk >> 2, c0 = (kk & 3) * 32;
#pragma unroll
            for (int mi = 0; mi < 7; mi++) {
                short8 af = *(const short8*)&win[(mi * 16 + l15 + kn) * CHP + c0 + q * 8];
#pragma unroll
                for (int ni = 0; ni < 2; ni++)
                    acc[mi][ni] = __builtin_amdgcn_mfma_f32_16x16x32_bf16(
                        af, *(short8*)&breg[ni][kk], acc[mi][ni], 0, 0, 0);
            }
        }
        // dump all acc -> Gld (Gld disjoint from win; other waves may still read win)
#pragma unroll
        for (int mi = 0; mi < 7; mi++)
#pragma unroll
            for (int ni = 0; ni < 2; ni++) {
                int g = (2 * w + ni) * 16 + l15;
#pragma unroll
                for (int r = 0; r < 4; r++)
                    Gld[(mi * 16 + q * 4 + r) * NGP + g] = acc[mi][ni][r];
            }
        __syncthreads();   // all MFMA win-reads + Gld writes complete

        // update: 14 (m,f) pairs per thread; write h into win + owned cols to global
#pragma unroll
        for (int j = 0; j < 14; j++) {
            int p = tid + j * 512;
            int m = p >> 6, f = p & 63;
            float gi = Gld[m * NGP + f]        + bias[f];
            float gf = Gld[m * NGP + 64 + f]   + bias[64 + f];
            float gc = Gld[m * NGP + 128 + f]  + bias[128 + f];
            float go = Gld[m * NGP + 192 + f]  + bias[192 + f];
            float iv = hsig(gi), fv = hsig(gf), ov = hsig(go);
            float cn = fv * cst[j] + iv * tanhf(gc);
            cst[j] = cn;
            int n = lo + m;
            if (n < N) {
                u16 hb = f2b(ov * tanhf(cn));
                win[(m + 1) * CHP + 64 + f] = hb;
                if ((unsigned)(n - n0) < 64u)
                    h1all[((long)t * B + bb) * N * 64 + n * 64 + f] = hb;
            }
        }
        if (t + 1 < T) stage_x(t + 1);
        __syncthreads();   // win writes (h + next x) visible before next MFMA
    }
}

// ---------- MFMA ConvLSTM step (verbatim R11; used for lstm2 only) ----------
template<int CIN, int F, int FL>
__global__ __launch_bounds__(512, 4)
void lstm_mfma(const u16* __restrict__ xin, const u16* __restrict__ hprev,
               u16* __restrict__ hnext, float* __restrict__ cst,
               const u16* __restrict__ Wt, const float* __restrict__ bias,
               const float* __restrict__ ssqp, int t) {
    constexpr int CH = CIN + F;
    constexpr int CHP = CH + 8;
    constexpr int K = 3 * CH;
    constexpr int NK = K / 32;
    constexpr int NGL = 4 * FL;
    constexpr int NGP = NGL + 4;
    constexpr int NI = NGL / 128;
    constexpr int BCH = NGL * 32;
    constexpr int GLD_USH = 32 * NGP * 2;
    constexpr int UNION_USH = (2 * BCH > GLD_USH) ? 2 * BCH : GLD_USH;
    constexpr int LOGFL = (FL == 64) ? 6 : 5;

    __shared__ __align__(16) u16 win[66 * CHP];
    __shared__ __align__(16) u16 ubuf[UNION_USH];
    u16* bch = ubuf;
    float* Gld = (float*)ubuf;

    int tid = threadIdx.x;
    int bb = blockIdx.y, n0 = blockIdx.x * 64, z = blockIdx.z;
    int w = tid >> 6, l15 = tid & 15, q = (tid >> 4) & 3;

    float scale = 1.f;
    if (ssqp) scale = rsqrtf(fmaxf(ssqp[bb * T + t], 1e-12f));

    constexpr int GRP = CH / 4;
    for (int i = tid; i < 66 * GRP; i += 512) {
        int row = i / GRP, g4 = (i - row * GRP) * 4;
        int n = n0 + row - 1;
        uint2 v{};
        if (n >= 0 && n < N) {
            if (g4 < CIN) {
                v = *(const uint2*)&xin[((long)bb * N + n) * CIN + g4];
                if (ssqp) {
                    u16 e0 = f2b(b2fu((u16)(v.x & 0xFFFF)) * scale);
                    u16 e1 = f2b(b2fu((u16)(v.x >> 16)) * scale);
                    u16 e2 = f2b(b2fu((u16)(v.y & 0xFFFF)) * scale);
                    u16 e3 = f2b(b2fu((u16)(v.y >> 16)) * scale);
                    v.x = (u32)e0 | ((u32)e1 << 16);
                    v.y = (u32)e2 | ((u32)e3 << 16);
                }
            } else if (t > 0) {
                v = *(const uint2*)&hprev[((long)bb * N + n) * F + (g4 - CIN)];
            }
        }
        *(uint2*)&win[row * CHP + g4] = v;
    }

    auto stage = [&](int kk, int bufi) {
#pragma unroll
        for (int it = 0; it < NGL / 128; ++it) {
            int P = it * 512 + tid;
            int r = P >> 2, u = P & 3;
            int gt = r >> LOGFL, fl = r & (FL - 1);
            long g = (long)gt * F + z * FL + fl;
            int k = kk * 32 + ((u ^ (r & 3)) << 3);
#if HAVE_ASYNC
            ASYNC16(Wt + g * K + k, &bch[bufi * BCH + P * 8]);
#else
            uint4 v = *(const uint4*)(Wt + g * K + k);
            *(uint4*)&bch[bufi * BCH + P * 8] = v;
#endif
        }
    };
    stage(0, 0);
    __syncthreads();

    floatx4 acc[4][NI] = {};
    for (int kk = 0; kk < NK; ++kk) {
        int cur = kk & 1;
        if (kk + 1 < NK) stage(kk + 1, 1 - cur);
        int kbase = kk * 32;
        int kn = kbase / CH, c0 = kbase - kn * CH;
        short8 af[4];
#pragma unroll
        for (int mi = 0; mi < 4; mi++)
            af[mi] = *(const short8*)&win[(mi * 16 + l15 + kn) * CHP + c0 + q * 8];
#pragma unroll
        for (int ni = 0; ni < NI; ni++) {
            int r = w * (NI * 16) + ni * 16 + l15;
            short8 bf = *(const short8*)&bch[cur * BCH + r * 32 + ((q ^ (r & 3)) << 3)];
#pragma unroll
            for (int mi = 0; mi < 4; mi++)
                acc[mi][ni] = __builtin_amdgcn_mfma_f32_16x16x32_bf16(af[mi], bf, acc[mi][ni], 0, 0, 0);
        }
        __syncthreads();
    }

    for (int h = 0; h < 2; ++h) {
#pragma unroll
        for (int mi2 = 0; mi2 < 2; ++mi2) {
            int mi = h * 2 + mi2;
#pragma unroll
            for (int ni = 0; ni < NI; ni++)
#pragma unroll
                for (int r = 0; r < 4; r++)
                    Gld[(mi2 * 16 + q * 4 + r) * NGP + w * (NI * 16) + ni * 16 + l15] = acc[mi][ni][r];
        }
        __syncthreads();
        for (int i = tid; i < 32 * FL; i += 512) {
            int m = i >> LOGFL, fl = i & (FL - 1);
            int fz = z * FL + fl;
            float gi = Gld[m * NGP + fl]          + bias[fz];
            float gf = Gld[m * NGP + FL + fl]     + bias[F + fz];
            float gc = Gld[m * NGP + 2 * FL + fl] + bias[2 * F + fz];
            float go = Gld[m * NGP + 3 * FL + fl] + bias[3 * F + fz];
            int n = n0 + h * 32 + m;
            long ci = ((long)bb * N + n) * F + fz;
            float cp = (t > 0) ? cst[ci] : 0.f;
            float iv = hsig(gi), fv = hsig(gf), ov = hsig(go);
            float cn = fv * cp + iv * tanhf(gc);
            cst[ci] = cn;
            hnext[ci] = f2b(ov * tanhf(cn));
        }
        __syncthreads();
    }
}

// ---------- final: l2norm per b over N*F2 (bf16 in), project 128->1, flag-dtype store ----------
__global__ void final_kernel(const u16* __restrict__ hT, const float* __restrict__ fcw,
                             const float* __restrict__ fcb, void* __restrict__ out,
                             const int* __restrict__ flag) {
    __shared__ float red[256];
    int b = blockIdx.x, tid = threadIdx.x;
    const u16* hb = hT + (long)b * N * 128;
    float s = 0.f;
    for (int i = tid; i < N * 128; i += 256) { float v = b2fu(hb[i]); s += v * v; }
    red[tid] = s; __syncthreads();
    for (int k = 128; k > 0; k >>= 1) {
        if (tid < k) red[tid] += red[tid + k];
        __syncthreads();
    }
    float scale = rsqrtf(fmaxf(red[0], 1e-12f));
    int n = tid;
    float acc = fcb[0];
    for (int c = 0; c < 128; c++) acc += b2fu(hb[n * 128 + c]) * scale * fcw[c];
    if (*flag) ((bf16*)out)[b * N + n] = __float2bfloat16(acc);
    else       ((float*)out)[b * N + n] = acc;
}

extern "C" void kernel_launch(void* const* d_in, const int* in_sizes, int n_in,
                              void* d_out, int out_size, void* d_ws, size_t ws_size,
                              hipStream_t stream) {
    float* ws = (float*)d_ws;
    u16* xs24   = (u16*)ws;                 // 24*B*N*64 u16 = 12,582,912 fl
    u16* c1all  = (u16*)(ws + 12582912);    // 26*B*N*64 u16 = 13,631,488 fl
    u16* h1all  = (u16*)(ws + 26214400);    // 24*B*N*64 u16 = 12,582,912 fl
    u16* h2A    = (u16*)(ws + 38797312);    // 1,048,576 fl
    u16* h2B    = (u16*)(ws + 39845888);    // 1,048,576 fl
    float* c2   = ws + 40894464;            // 2,097,152 fl
    u16* Wt1    = (u16*)(ws + 42991616);    // 49,152 fl
    u16* Wt2    = (u16*)(ws + 43040768);    // 147,456 fl
    u16* w2b    = (u16*)(ws + 43188224);    // 18,432 fl
    float* w1c  = ws + 43206656;            // 576
    float* bb1  = ws + 43207232;            // 64
    float* bb2  = ws + 43207296;            // 64
    float* bg1  = ws + 43207360;            // 256
    float* bg2  = ws + 43207616;            // 512
    float* fcwf = ws + 43208128;            // 128
    float* fcbf = ws + 43208256;            // 1
    float* ssq  = ws + 43208257;            // 1536
    int*   flag = (int*)(ws + 43209793);    // total ~43.2M fl = 173 MB

    init_flag<<<1, 1, 0, stream>>>(flag);
    detect_scan<<<32, 256, 0, stream>>>((const u16*)d_in[0], flag);

    CvtPack pk;
    pk.d[0] = {d_in[1],  w1c,  576};
    pk.d[1] = {d_in[2],  bb1,  64};
    pk.d[2] = {d_in[4],  bb2,  64};
    pk.d[3] = {d_in[7],  bg1,  256};
    pk.d[4] = {d_in[10], bg2,  512};
    pk.d[5] = {d_in[11], fcwf, 128};
    pk.d[6] = {d_in[12], fcbf, 1};
    pk.d[7] = {nullptr,  ssq,  B * T};
    cvt_pack<<<8, 256, 0, stream>>>(pk, flag);

    repack_w<<<(256 * 384 + 255) / 256, 256, 0, stream>>>(d_in[5], d_in[6], Wt1, 64, 64, flag);
    repack_w<<<(512 * 576 + 255) / 256, 256, 0, stream>>>(d_in[8], d_in[9], Wt2, 64, 128, flag);
    repack_w2<<<(64 * 576 + 255) / 256, 256, 0, stream>>>(d_in[3], w2b, flag);

    conv1_all<<<dim3(26, B), 256, 0, stream>>>(d_in[0], w1c, bb1, c1all, flag);
    conv_mfma<<<dim3(4, B, 24), 256, 0, stream>>>(c1all, w2b, bb2, xs24, ssq);

    // entire lstm1 chain in one persistent dispatch (c1 lives in registers)
    lstm1_chain<<<dim3(4, B), 512, 0, stream>>>(xs24, h1all, Wt1, bg1, ssq);

    for (int t = 0; t < T; t++) {
        const u16* h2p = (t & 1) ? h2A : h2B;
        u16* h2n = (t & 1) ? h2B : h2A;
        lstm_mfma<64, 128, 64><<<dim3(4, B, 2), 512, 0, stream>>>(
            h1all + (long)t * B * N * 64, h2p, h2n, c2, Wt2, bg2, nullptr, t);
    }
    // t=23 (odd) wrote h2B
    final_kernel<<<B, 256, 0, stream>>>(h2B, fcwf, fcbf, d_out, flag);
}